// Round 6
// baseline (466.080 us; speedup 1.0000x reference)
//
#include <hip/hip_runtime.h>
#include <cstdint>
#include <cstddef>

typedef __attribute__((ext_vector_type(4))) float f32x4;
typedef __attribute__((ext_vector_type(8))) _Float16 half8v;
typedef __attribute__((ext_vector_type(2))) _Float16 half2v;

static inline int cdiv(int a, int b){ return (a + b - 1) / b; }

// ---------------- fused: weight-convert (blocks 0..223) || degree count (rest) ----------------

__global__ __launch_bounds__(256) void wcvt_count_kernel(const float* __restrict__ W1, _Float16* __restrict__ W1t,
                                                         const float* __restrict__ W2, _Float16* __restrict__ W2t,
                                                         const float* __restrict__ W3, _Float16* __restrict__ W3t,
                                                         const int* __restrict__ dst, int* __restrict__ counts, int E){
  int b = blockIdx.x;
  if (b < 224){
    int i = b * 256 + threadIdx.x;
    if (b < 128){
      int k = i / 128, n = i & 127;
      W1t[(size_t)n * 256 + k] = (_Float16)W1[i];
    } else if (b < 192){
      int j = i - 128 * 256;
      int k = j / 128, n = j & 127;
      W2t[(size_t)n * 128 + k] = (_Float16)W2[j];
    } else {
      int j = i - 192 * 256;
      int k = j / 64, n = j & 63;
      W3t[(size_t)n * 128 + k] = (_Float16)W3[j];
    }
    return;
  }
  int cb = b - 224;
  int base = cb * 1024 + threadIdx.x;
  #pragma unroll
  for (int j = 0; j < 4; j++){
    int i = base + j * 256;
    if (i < E) atomicAdd(&counts[__builtin_nontemporal_load(dst + i)], 1);
  }
}

// ---------------- block partial sums (+ fused dinv) ----------------

__global__ __launch_bounds__(256) void partial_dinv_kernel(const int* __restrict__ counts, int* __restrict__ bsum,
                                                           float* __restrict__ dinv, int n){
  __shared__ int sdata[256];
  int b = blockIdx.x, t = threadIdx.x;
  int base = b * 1024 + t * 4;
  int s = 0;
  #pragma unroll
  for (int i = 0; i < 4; i++){
    if (base + i < n){
      int c = counts[base + i];
      s += c;
      dinv[base + i] = rsqrtf((float)c + 1.0f);
    }
  }
  sdata[t] = s; __syncthreads();
  for (int off = 128; off > 0; off >>= 1){
    if (t < off) sdata[t] += sdata[t + off];
    __syncthreads();
  }
  if (t == 0) bsum[b] = sdata[0];
}

__global__ void scan_partials_kernel(const int* __restrict__ bsum, int* __restrict__ bsum_ex,
                                     int* __restrict__ row_off, int nblocks, int n){
  int run = 0;
  for (int i = 0; i < nblocks; i++){ bsum_ex[i] = run; run += bsum[i]; }
  row_off[n] = run;
}

__global__ __launch_bounds__(256) void scan_chunk_kernel(const int* __restrict__ counts, const int* __restrict__ bsum_ex,
                                                         int* __restrict__ row_off, int n){
  __shared__ int sdata[256];
  int b = blockIdx.x, t = threadIdx.x;
  int base = b * 1024 + t * 4;
  int c0 = (base + 0 < n) ? counts[base + 0] : 0;
  int c1 = (base + 1 < n) ? counts[base + 1] : 0;
  int c2 = (base + 2 < n) ? counts[base + 2] : 0;
  int c3 = (base + 3 < n) ? counts[base + 3] : 0;
  int tsum = c0 + c1 + c2 + c3;
  sdata[t] = tsum; __syncthreads();
  for (int off = 1; off < 256; off <<= 1){
    int v = (t >= off) ? sdata[t - off] : 0;
    __syncthreads();
    sdata[t] += v;
    __syncthreads();
  }
  int run = bsum_ex[b] + sdata[t] - tsum;
  if (base + 0 < n){ row_off[base + 0] = run; run += c0; }
  if (base + 1 < n){ row_off[base + 1] = run; run += c1; }
  if (base + 2 < n){ row_off[base + 2] = run; run += c2; }
  if (base + 3 < n){ row_off[base + 3] = run; run += c3; }
}

// ---------------- XCD-partitioned CSR fill (standalone, nt edge streams) ----------------
// block fb: xcd = fb&7 (round-robin dispatch heuristic), handles dst in [xcd*PART, xcd*PART+PART).
// nt loads keep the 12.8MB/XCD edge stream out of L2 so the ~800KB/XCD csr_src dirty-line
// working set survives until lines are full -> writeback ~4B/edge instead of 64B/edge.

__global__ __launch_bounds__(256) void fill_kernel(const int* __restrict__ src, const int* __restrict__ dst,
                                                   const int* __restrict__ row_off, int* __restrict__ cursor,
                                                   int* __restrict__ csr_src, int E, int N, int NC){
  int fb = blockIdx.x;
  int xcd = fb & 7, chunk = fb >> 3;
  int PART = (N + 7) >> 3;
  int lo = xcd * PART;
  int hi = lo + PART; if (hi > N) hi = N;
  int CH = (E + NC - 1) / NC;
  int e0 = chunk * CH;
  int e1 = e0 + CH; if (e1 > E) e1 = E;
  for (int i = e0 + threadIdx.x; i < e1; i += 256){
    int d = __builtin_nontemporal_load(dst + i);
    if (d >= lo && d < hi){
      int s = __builtin_nontemporal_load(src + i);
      int p = row_off[d] + atomicAdd(&cursor[d], 1);
      csr_src[p] = s;
    }
  }
}

// ---------------- MFMA GEMM: C16[M x BN] = fp16(A @ Bt^T), Bt is [BN x K] fp16 ----------------
// BM=128, BK=32, 4 waves. v_mfma_f32_16x16x32_f16:
//   A: lane l row (l&15), k = 8*(l>>4)+{0..7}; B: lane l col (l&15), same k
//   D: lane l reg r -> row = 4*(l>>4)+r, col = (l&15)

template<int BN, bool A32IN>
__global__ __launch_bounds__(256) void mgemm_kernel(const void* __restrict__ Ain, const _Float16* __restrict__ Bt,
                                                    _Float16* __restrict__ C16, int M, int K){
  constexpr int BM = 128, LD = 40;   // stride 40 halves: 16B-aligned rows, <=2-way bank aliasing
  constexpr int MF = (BN == 128) ? 4 : 2;
  __shared__ _Float16 As[BM * LD];
  __shared__ _Float16 Bs[BN * LD];
  const float*    A32 = (const float*)Ain;
  const _Float16* A16 = (const _Float16*)Ain;
  int t = threadIdx.x;
  int w = t >> 6, l = t & 63;
  int m0 = blockIdx.x * BM;
  int wm = (BN == 128) ? (w >> 1) * 64 : w * 32;
  int wn = (BN == 128) ? (w & 1) * 64 : 0;
  int lr = l & 15;
  int kg = (l >> 4) * 8;

  f32x4 acc[MF][4];
  #pragma unroll
  for (int i = 0; i < MF; i++)
    #pragma unroll
    for (int j = 0; j < 4; j++){
      f32x4 z = {0.f, 0.f, 0.f, 0.f};
      acc[i][j] = z;
    }

  for (int k0 = 0; k0 < K; k0 += 32){
    __syncthreads();
    #pragma unroll
    for (int j = 0; j < (BM * 4) / 256; j++){
      int i = t + j * 256;
      int row = i >> 2, c = i & 3;
      int gr = m0 + row;
      half8v hv = {(_Float16)0, (_Float16)0, (_Float16)0, (_Float16)0,
                   (_Float16)0, (_Float16)0, (_Float16)0, (_Float16)0};
      if (gr < M){
        if (A32IN){
          const float* ap = A32 + (size_t)gr * K + k0 + c * 8;
          float4 f0 = *reinterpret_cast<const float4*>(ap);
          float4 f1 = *reinterpret_cast<const float4*>(ap + 4);
          hv[0] = (_Float16)f0.x; hv[1] = (_Float16)f0.y; hv[2] = (_Float16)f0.z; hv[3] = (_Float16)f0.w;
          hv[4] = (_Float16)f1.x; hv[5] = (_Float16)f1.y; hv[6] = (_Float16)f1.z; hv[7] = (_Float16)f1.w;
        } else {
          hv = *reinterpret_cast<const half8v*>(A16 + (size_t)gr * K + k0 + c * 8);
        }
      }
      *reinterpret_cast<half8v*>(&As[row * LD + c * 8]) = hv;
    }
    #pragma unroll
    for (int j = 0; j < (BN * 4) / 256; j++){
      int i = t + j * 256;
      int row = i >> 2, c = i & 3;
      *reinterpret_cast<half8v*>(&Bs[row * LD + c * 8]) =
        *reinterpret_cast<const half8v*>(Bt + (size_t)row * K + k0 + c * 8);
    }
    __syncthreads();
    half8v af[MF];
    #pragma unroll
    for (int mf = 0; mf < MF; mf++)
      af[mf] = *reinterpret_cast<const half8v*>(&As[(wm + mf * 16 + lr) * LD + kg]);
    #pragma unroll
    for (int nf = 0; nf < 4; nf++){
      half8v bf = *reinterpret_cast<const half8v*>(&Bs[(wn + nf * 16 + lr) * LD + kg]);
      #pragma unroll
      for (int mf = 0; mf < MF; mf++)
        acc[mf][nf] = __builtin_amdgcn_mfma_f32_16x16x32_f16(af[mf], bf, acc[mf][nf], 0, 0, 0);
    }
  }
  #pragma unroll
  for (int mf = 0; mf < MF; mf++){
    #pragma unroll
    for (int r = 0; r < 4; r++){
      int row = m0 + wm + mf * 16 + (l >> 4) * 4 + r;
      if (row < M){
        #pragma unroll
        for (int nf = 0; nf < 4; nf++)
          C16[(size_t)row * BN + wn + nf * 16 + lr] = (_Float16)acc[mf][nf][r];
      }
    }
  }
}

// ---------------- aggregation (fp16 gather): out = relu(di*(sum dinv_s h_s) + di^2 h_i + b) ----------------

__global__ __launch_bounds__(256) void agg128h_kernel(const _Float16* __restrict__ h16, const int* __restrict__ row_off,
                                                      const int* __restrict__ csr_src, const float* __restrict__ dinv,
                                                      const float* __restrict__ bias, _Float16* __restrict__ out16, int n){
  int node = blockIdx.x * 4 + (threadIdx.x >> 6);
  if (node >= n) return;
  int lane = threadIdx.x & 63;
  int e = row_off[node], eend = row_off[node + 1];
  float di = dinv[node];
  float ax = 0.f, ay = 0.f;
  for (; e + 8 <= eend; e += 8){
    int s[8]; float w[8]; half2v v[8];
    #pragma unroll
    for (int i = 0; i < 8; i++) s[i] = csr_src[e + i];
    #pragma unroll
    for (int i = 0; i < 8; i++) w[i] = dinv[s[i]];
    #pragma unroll
    for (int i = 0; i < 8; i++)
      v[i] = *reinterpret_cast<const half2v*>(h16 + (size_t)s[i] * 128 + lane * 2);
    #pragma unroll
    for (int i = 0; i < 8; i++){
      ax = fmaf(w[i], (float)v[i][0], ax);
      ay = fmaf(w[i], (float)v[i][1], ay);
    }
  }
  for (; e < eend; ++e){
    int s = csr_src[e];
    float w = dinv[s];
    half2v v = *reinterpret_cast<const half2v*>(h16 + (size_t)s * 128 + lane * 2);
    ax = fmaf(w, (float)v[0], ax);
    ay = fmaf(w, (float)v[1], ay);
  }
  half2v hv = *reinterpret_cast<const half2v*>(h16 + (size_t)node * 128 + lane * 2);
  float2 bv = *reinterpret_cast<const float2*>(bias + lane * 2);
  float ox = fmaxf(fmaf(di, ax, di * di * (float)hv[0]) + bv.x, 0.f);
  float oy = fmaxf(fmaf(di, ay, di * di * (float)hv[1]) + bv.y, 0.f);
  half2v o; o[0] = (_Float16)ox; o[1] = (_Float16)oy;
  *reinterpret_cast<half2v*>(out16 + (size_t)node * 128 + lane * 2) = o;
}

__global__ __launch_bounds__(256) void agg64h_kernel(const _Float16* __restrict__ h16, const int* __restrict__ row_off,
                                                     const int* __restrict__ csr_src, const float* __restrict__ dinv,
                                                     const float* __restrict__ bias, float* __restrict__ out, int n){
  int node = blockIdx.x * 4 + (threadIdx.x >> 6);
  if (node >= n) return;
  int lane = threadIdx.x & 63;
  int e = row_off[node], eend = row_off[node + 1];
  float di = dinv[node];
  float ax = 0.f;
  for (; e + 8 <= eend; e += 8){
    int s[8]; float w[8]; _Float16 v[8];
    #pragma unroll
    for (int i = 0; i < 8; i++) s[i] = csr_src[e + i];
    #pragma unroll
    for (int i = 0; i < 8; i++) w[i] = dinv[s[i]];
    #pragma unroll
    for (int i = 0; i < 8; i++) v[i] = h16[(size_t)s[i] * 64 + lane];
    #pragma unroll
    for (int i = 0; i < 8; i++) ax = fmaf(w[i], (float)v[i], ax);
  }
  for (; e < eend; ++e){
    int s = csr_src[e];
    ax = fmaf(dinv[s], (float)h16[(size_t)s * 64 + lane], ax);
  }
  float hv = (float)h16[(size_t)node * 64 + lane];
  float o = fmaxf(fmaf(di, ax, di * di * hv) + bias[lane], 0.f);
  out[(size_t)node * 64 + lane] = o;
}

// ---------------- classifier ----------------

__global__ __launch_bounds__(256) void cls_kernel(const float* __restrict__ g, const float* __restrict__ Wc,
                                                  const float* __restrict__ bc, float* __restrict__ out, int n){
  int node = blockIdx.x * 4 + (threadIdx.x >> 6);
  if (node >= n) return;
  int lane = threadIdx.x & 63;
  float v = g[(size_t)node * 64 + lane] * Wc[lane];
  #pragma unroll
  for (int off = 32; off > 0; off >>= 1) v += __shfl_down(v, off);
  if (lane == 0) out[node] = v + bc[0];
}

// ---------------- launch ----------------

extern "C" void kernel_launch(void* const* d_in, const int* in_sizes, int n_in,
                              void* d_out, int out_size, void* d_ws, size_t ws_size,
                              hipStream_t stream){
  const float* x  = (const float*)d_in[0];
  const int*   ei = (const int*)d_in[1];
  const float* W1 = (const float*)d_in[2];
  const float* b1 = (const float*)d_in[3];
  const float* W2 = (const float*)d_in[4];
  const float* b2 = (const float*)d_in[5];
  const float* W3 = (const float*)d_in[6];
  const float* b3 = (const float*)d_in[7];
  const float* Wc = (const float*)d_in[8];
  const float* bc = (const float*)d_in[9];
  float* out = (float*)d_out;

  int N = in_sizes[0] / 256;
  int E = in_sizes[1] / 2;
  const int* src = ei;
  const int* dst = ei + E;

  char* ws = (char*)d_ws;
  size_t off = 0;
  auto alloc = [&](size_t bytes) -> char* {
    char* p = ws + off;
    off += (bytes + 511) & ~(size_t)511;
    return p;
  };
  int*      counts  = (int*)     alloc((size_t)N * 4);   // reused as cursor after scan
  float*    dinv    = (float*)   alloc((size_t)N * 4);
  int*      row_off = (int*)     alloc(((size_t)N + 1) * 4);
  int*      bsum    = (int*)     alloc(1024);
  int*      bsum_ex = (int*)     alloc(1024);
  int*      csr_src = (int*)     alloc((size_t)E * 4);
  _Float16* bufH    = (_Float16*)alloc((size_t)N * 128 * 2);  // gemm outputs
  _Float16* bufG    = (_Float16*)alloc((size_t)N * 128 * 2);  // agg outputs (fp16)
  float*    bufF    = (float*)   alloc((size_t)N * 64 * 4);   // layer-3 agg output (fp32)
  _Float16* W1t     = (_Float16*)alloc((size_t)256 * 128 * 2);
  _Float16* W2t     = (_Float16*)alloc((size_t)128 * 128 * 2);
  _Float16* W3t     = (_Float16*)alloc((size_t)128 * 64 * 2);

  int NB = (N + 1023) / 1024;

  // K1: wcvt (224 blocks) || degree count
  hipMemsetAsync(counts, 0, (size_t)N * 4, stream);
  wcvt_count_kernel<<<224 + cdiv(E, 1024), 256, 0, stream>>>(W1, W1t, W2, W2t, W3, W3t, dst, counts, E);
  // K2: scan chain (+ dinv fused)
  partial_dinv_kernel<<<NB, 256, 0, stream>>>(counts, bsum, dinv, N);
  scan_partials_kernel<<<1, 1, 0, stream>>>(bsum, bsum_ex, row_off, NB, N);
  scan_chunk_kernel<<<NB, 256, 0, stream>>>(counts, bsum_ex, row_off, N);
  hipMemsetAsync(counts, 0, (size_t)N * 4, stream);   // counts -> cursor
  // K3: XCD-partitioned fill (standalone)
  {
    int NC = 256;                     // edge chunks per XCD; fill blocks = 8*NC
    fill_kernel<<<8 * NC, 256, 0, stream>>>(src, dst, row_off, counts, csr_src, E, N, NC);
  }
  // layer 1: x[N,256] @ W1 -> bufH (fp16); agg -> bufG (fp16)
  mgemm_kernel<128, true ><<<cdiv(N, 128), 256, 0, stream>>>(x, W1t, bufH, N, 256);
  agg128h_kernel<<<cdiv(N, 4), 256, 0, stream>>>(bufH, row_off, csr_src, dinv, b1, bufG, N);
  // layer 2
  mgemm_kernel<128, false><<<cdiv(N, 128), 256, 0, stream>>>(bufG, W2t, bufH, N, 128);
  agg128h_kernel<<<cdiv(N, 4), 256, 0, stream>>>(bufH, row_off, csr_src, dinv, b2, bufG, N);
  // layer 3 (128 -> 64)
  mgemm_kernel<64, false><<<cdiv(N, 128), 256, 0, stream>>>(bufG, W3t, bufH, N, 128);
  agg64h_kernel<<<cdiv(N, 4), 256, 0, stream>>>(bufH, row_off, csr_src, dinv, b3, bufF, N);
  // classifier
  cls_kernel<<<cdiv(N, 4), 256, 0, stream>>>(bufF, Wc, bc, out, N);
}